// Round 2
// baseline (12607.382 us; speedup 1.0000x reference)
//
#include <hip/hip_runtime.h>
#include <math.h>

// ---------------------------------------------------------------------------
// Sender: LSTM + RelaxedOneHotCategorical straight-through decode, 32 steps.
// Round 2: fix Gumbel bits — JAX partitionable threefry returns x0 ^ x1 for
// 32-bit draws (jax/_src/prng.py::_threefry_random_bits_partitionable),
// not the x1 word alone.
// ---------------------------------------------------------------------------

#define BMM 128
#define BNN 128
#define BKK 8
#define TM 8
#define TN 8

// C[m,n] = sum_k Aeff[m,k]*Beff[n,k] + bias0[n] (+ bias1[n])
// K region split at Ksplit: k<Ksplit -> (A0,lda0,B0,ldb0), else (A1,lda1,B1,ldb1).
// If czero != null, also writes 0 to czero at the same [m,n] (ld = ldc).
__global__ __launch_bounds__(256) void gemm_nt_kernel(
    const float* __restrict__ A0, int lda0,
    const float* __restrict__ A1, int lda1,
    const float* __restrict__ B0, int ldb0,
    const float* __restrict__ B1, int ldb1,
    int Ksplit, int K,
    const float* __restrict__ bias0, const float* __restrict__ bias1,
    float* __restrict__ C, int ldc,
    float* __restrict__ czero)
{
  __shared__ float As[BKK][BMM];
  __shared__ float Bs[BKK][BNN];
  const int tid = threadIdx.x;
  const int bm = blockIdx.y * BMM;
  const int bn = blockIdx.x * BNN;
  const int tx = tid & 15;
  const int ty = tid >> 4;
  const int lrow = tid >> 1;        // 0..127
  const int lcol = (tid & 1) * 4;   // 0 or 4

  float acc[TM][TN];
#pragma unroll
  for (int i = 0; i < TM; ++i)
#pragma unroll
    for (int j = 0; j < TN; ++j) acc[i][j] = 0.0f;

  const int nkt = K / BKK;
  for (int kt = 0; kt < nkt; ++kt) {
    const int kg = kt * BKK;
    const float* Ap; const float* Bp; int la, lb, kk;
    if (kg < Ksplit) { Ap = A0; la = lda0; Bp = B0; lb = ldb0; kk = kg; }
    else             { Ap = A1; la = lda1; Bp = B1; lb = ldb1; kk = kg - Ksplit; }
    const float4 av = *(const float4*)(Ap + (size_t)(bm + lrow) * la + kk + lcol);
    const float4 bv = *(const float4*)(Bp + (size_t)(bn + lrow) * lb + kk + lcol);
    __syncthreads();
    As[lcol + 0][lrow] = av.x; As[lcol + 1][lrow] = av.y;
    As[lcol + 2][lrow] = av.z; As[lcol + 3][lrow] = av.w;
    Bs[lcol + 0][lrow] = bv.x; Bs[lcol + 1][lrow] = bv.y;
    Bs[lcol + 2][lrow] = bv.z; Bs[lcol + 3][lrow] = bv.w;
    __syncthreads();
#pragma unroll
    for (int k = 0; k < BKK; ++k) {
      float a[TM], bb[TN];
#pragma unroll
      for (int i = 0; i < TM; ++i) a[i] = As[k][ty * TM + i];
#pragma unroll
      for (int j = 0; j < TN; ++j) bb[j] = Bs[k][tx * TN + j];
#pragma unroll
      for (int i = 0; i < TM; ++i)
#pragma unroll
        for (int j = 0; j < TN; ++j)
          acc[i][j] = fmaf(a[i], bb[j], acc[i][j]);
    }
  }

  float b0[TN], b1[TN];
  const bool has1 = (bias1 != nullptr);
#pragma unroll
  for (int j = 0; j < TN; ++j) {
    const int col = bn + tx * TN + j;
    b0[j] = bias0[col];
    b1[j] = has1 ? bias1[col] : 0.0f;
  }
#pragma unroll
  for (int i = 0; i < TM; ++i) {
    const int row = bm + ty * TM + i;
    float* crow = C + (size_t)row * ldc + bn + tx * TN;
    float vals[TN];
#pragma unroll
    for (int j = 0; j < TN; ++j) {
      float v = acc[i][j] + b0[j];       // matches ref: (dot + b_ih) + b_hh
      if (has1) v = v + b1[j];
      vals[j] = v;
    }
    *(float4*)(crow)     = make_float4(vals[0], vals[1], vals[2], vals[3]);
    *(float4*)(crow + 4) = make_float4(vals[4], vals[5], vals[6], vals[7]);
    if (czero) {
      const float4 z4 = make_float4(0.f, 0.f, 0.f, 0.f);
      float* zrow = czero + (size_t)row * ldc + bn + tx * TN;
      *(float4*)zrow = z4; *(float4*)(zrow + 4) = z4;
    }
  }
}

// --------------------------- threefry / gumbel -----------------------------

__device__ __forceinline__ unsigned tf_rotl(unsigned x, int r) {
  return (x << r) | (x >> (32 - r));
}

// JAX threefry2x32-20, key = (0, 42). Partitionable scheme: per-element
// counter (hi=0, lo=idx); 32-bit draw = x0_out ^ x1_out.
__device__ inline float gumbel_at(unsigned idx) {
  const unsigned ks0 = 0u;
  const unsigned ks1 = 42u;
  const unsigned ks2 = 0x1BD11BDAu ^ ks0 ^ ks1;
  unsigned x0 = 0u + ks0;     // counter hi word
  unsigned x1 = idx + ks1;    // counter lo word
#define TFR(rot) { x0 += x1; x1 = tf_rotl(x1, rot); x1 ^= x0; }
  TFR(13) TFR(15) TFR(26) TFR(6)
  x0 += ks1; x1 += ks2 + 1u;
  TFR(17) TFR(29) TFR(16) TFR(24)
  x0 += ks2; x1 += ks0 + 2u;
  TFR(13) TFR(15) TFR(26) TFR(6)
  x0 += ks0; x1 += ks1 + 3u;
  TFR(17) TFR(29) TFR(16) TFR(24)
  x0 += ks1; x1 += ks2 + 4u;
  TFR(13) TFR(15) TFR(26) TFR(6)
  x0 += ks2; x1 += ks0 + 5u;
#undef TFR
  const unsigned bits = x0 ^ x1;   // partitionable 32-bit draw
  const float f = __uint_as_float((bits >> 9) | 0x3F800000u) - 1.0f;
  const float tiny = 1.17549435082228751e-38f;       // finfo(f32).tiny (normal)
  const float u = fmaxf(tiny, f * (1.0f - tiny) + tiny);  // (1-tiny) folds to 1.0f, as in XLA
  return -logf(-logf(u));
}

// ------------------------------ small kernels ------------------------------

__global__ void init_out0_kernel(float* __restrict__ out, int* __restrict__ token,
                                 float* __restrict__ scale,
                                 const int* __restrict__ startp, int Tp1, int V) {
  const int b = blockIdx.x;
  const int start = *startp;
  const size_t base = (size_t)b * Tp1 * V;
  for (int v = threadIdx.x; v < V; v += blockDim.x)
    out[base + v] = (v == start) ? 1.0f : 0.0f;
  if (threadIdx.x == 0) { token[b] = start; scale[b] = 1.0f; }
}

__global__ void gather_emb_kernel(const float* __restrict__ emb,
                                  const int* __restrict__ token,
                                  const float* __restrict__ scale,
                                  float* __restrict__ embbuf, int E) {
  const int b = blockIdx.x;
  const int e = threadIdx.x;            // blockDim.x == E
  embbuf[(size_t)b * E + e] = scale[b] * emb[(size_t)token[b] * E + e];
}

__device__ __forceinline__ float sigm(float x) { return 1.0f / (1.0f + expf(-x)); }

__global__ void lstm_cell_kernel(const float* __restrict__ gates,
                                 float* __restrict__ cbuf,
                                 float* __restrict__ hbuf, int H) {
  const int n = blockIdx.x * blockDim.x + threadIdx.x;
  const int b = blockIdx.y;
  const size_t gbase = (size_t)b * 4 * H;
  const float gi = gates[gbase + n];
  const float gf = gates[gbase + H + n];
  const float gg = gates[gbase + 2 * H + n];
  const float go = gates[gbase + 3 * H + n];
  const size_t off = (size_t)b * H + n;
  const float c = cbuf[off];
  // block FMA contraction: ref computes mul, mul, add with separate roundings
  const float cn = __fadd_rn(__fmul_rn(sigm(gf), c), __fmul_rn(sigm(gi), tanhf(gg)));
  const float hn = __fmul_rn(sigm(go), tanhf(cn));
  cbuf[off] = cn;
  hbuf[off] = hn;
}

// One block (256 thr) per batch row; V must be 4096 (16 elems/thread).
__global__ __launch_bounds__(256) void sample_kernel(
    const float* __restrict__ logits,   // [B, V]
    float* __restrict__ out,            // [B, Tp1, V]
    int* __restrict__ token, float* __restrict__ scale,
    int step, int Tp1, int V, int B)
{
  const int b = blockIdx.x;
  const int tid = threadIdx.x;
  const int lane = tid & 63, wv = tid >> 6;
  __shared__ float sh_m[4], sh_se[4], sh_zm[4], sh_s2[4], sh_av[4];
  __shared__ int sh_ai[4];

  const float* lrow = logits + (size_t)b * V;
  float l[16];
#pragma unroll
  for (int j = 0; j < 16; ++j) l[j] = lrow[tid + 256 * j];

  // 1) row max of logits
  float m = -INFINITY;
#pragma unroll
  for (int j = 0; j < 16; ++j) m = fmaxf(m, l[j]);
  for (int o = 32; o > 0; o >>= 1) m = fmaxf(m, __shfl_down(m, o, 64));
  if (lane == 0) sh_m[wv] = m;
  __syncthreads();
  m = fmaxf(fmaxf(sh_m[0], sh_m[1]), fmaxf(sh_m[2], sh_m[3]));

  // 2) logsumexp of shifted (ref: shifted - log(sum(exp(shifted))))
  float se = 0.f;
#pragma unroll
  for (int j = 0; j < 16; ++j) { l[j] = l[j] - m; se += expf(l[j]); }
  for (int o = 32; o > 0; o >>= 1) se += __shfl_down(se, o, 64);
  if (lane == 0) sh_se[wv] = se;
  __syncthreads();
  se = ((sh_se[0] + sh_se[1]) + sh_se[2]) + sh_se[3];
  const float lse = logf(se);

  // 3) z = (logp + gumbel) / tau
  const unsigned ibase = ((unsigned)step * (unsigned)B + (unsigned)b) * (unsigned)V;
#pragma unroll
  for (int j = 0; j < 16; ++j) {
    const unsigned v = (unsigned)(tid + 256 * j);
    const float g = gumbel_at(ibase + v);
    l[j] = ((l[j] - lse) + g) / 1.2f;
  }

  // 4) zmax
  float zm = -INFINITY;
#pragma unroll
  for (int j = 0; j < 16; ++j) zm = fmaxf(zm, l[j]);
  for (int o = 32; o > 0; o >>= 1) zm = fmaxf(zm, __shfl_down(zm, o, 64));
  if (lane == 0) sh_zm[wv] = zm;
  __syncthreads();
  zm = fmaxf(fmaxf(sh_zm[0], sh_zm[1]), fmaxf(sh_zm[2], sh_zm[3]));

  // 5) e = exp(z - zmax), sum
  float s2 = 0.f;
#pragma unroll
  for (int j = 0; j < 16; ++j) { l[j] = expf(l[j] - zm); s2 += l[j]; }
  for (int o = 32; o > 0; o >>= 1) s2 += __shfl_down(s2, o, 64);
  if (lane == 0) sh_s2[wv] = s2;
  __syncthreads();
  s2 = ((sh_s2[0] + sh_s2[1]) + sh_s2[2]) + sh_s2[3];

  // 6) y = e / s2; argmax with first-index tie-break (ref: jnp.argmax on y)
  float bv = -INFINITY; int bi = 0x7fffffff;
#pragma unroll
  for (int j = 0; j < 16; ++j) {
    const float y = l[j] / s2;
    const int v = tid + 256 * j;
    if (y > bv || (y == bv && v < bi)) { bv = y; bi = v; }
  }
  for (int o = 32; o > 0; o >>= 1) {
    const float ov = __shfl_down(bv, o, 64);
    const int oi = __shfl_down(bi, o, 64);
    if (ov > bv || (ov == bv && oi < bi)) { bv = ov; bi = oi; }
  }
  if (lane == 0) { sh_av[wv] = bv; sh_ai[wv] = bi; }
  __syncthreads();
  bv = sh_av[0]; bi = sh_ai[0];
#pragma unroll
  for (int w = 1; w < 4; ++w) {
    const float ov = sh_av[w]; const int oi = sh_ai[w];
    if (ov > bv || (ov == bv && oi < bi)) { bv = ov; bi = oi; }
  }

  const float sc = (1.0f - bv) + bv;  // straight-through value at argmax
  float* orow = out + ((size_t)b * Tp1 + (step + 1)) * V;
#pragma unroll
  for (int j = 0; j < 16; ++j) {
    const int v = tid + 256 * j;
    orow[v] = (v == bi) ? sc : 0.0f;
  }
  if (tid == 0) { token[b] = bi; scale[b] = sc; }
}

// ------------------------------- host side ---------------------------------

extern "C" void kernel_launch(void* const* d_in, const int* in_sizes, int n_in,
                              void* d_out, int out_size, void* d_ws, size_t ws_size,
                              hipStream_t stream) {
  const float* t     = (const float*)d_in[0];
  const float* emb   = (const float*)d_in[1];
  const float* affw  = (const float*)d_in[2];
  const float* affb  = (const float*)d_in[3];
  const float* wih   = (const float*)d_in[4];
  const float* whh   = (const float*)d_in[5];
  const float* bih   = (const float*)d_in[6];
  const float* bhh   = (const float*)d_in[7];
  const float* lpw   = (const float*)d_in[8];
  const float* lpb   = (const float*)d_in[9];
  const int*   start = (const int*)d_in[10];
  float* out = (float*)d_out;

  const int H = in_sizes[3];             // 1024
  const int V = in_sizes[9];             // 4096
  const int E = in_sizes[1] / V;         // 256
  const int F = in_sizes[2] / H;         // 2048
  const int B = in_sizes[0] / F;         // 1024
  const int Tp1 = out_size / (B * V);    // 33
  const int T = Tp1 - 1;                 // 32

  // workspace layout (floats); total ~25 MB
  float* ws     = (float*)d_ws;
  float* hbuf   = ws;                              // [B, H]
  float* cbuf   = hbuf + (size_t)B * H;            // [B, H]
  float* embbuf = cbuf + (size_t)B * H;            // [B, E]
  float* glbuf  = embbuf + (size_t)B * E;          // [B, 4H] == [B, V], shared gates/logits
  int*   token  = (int*)(glbuf + (size_t)B * 4 * H);
  float* scale  = (float*)(token + B);
  (void)ws_size; (void)n_in;

  // init: out slice 0 (one-hot start), token/scale
  init_out0_kernel<<<B, 256, 0, stream>>>(out, token, scale, start, Tp1, V);

  // h0 = t @ aff_w.T + aff_b  -> hbuf; also zero cbuf
  gemm_nt_kernel<<<dim3(H / BNN, B / BMM), 256, 0, stream>>>(
      t, F, t, F, affw, F, affw, F, F, F, affb, nullptr, hbuf, H, cbuf);

  for (int s = 0; s < T; ++s) {
    // emb[b] = scale[b] * embedding[token[b]]
    gather_emb_kernel<<<B, E, 0, stream>>>(emb, token, scale, embbuf, E);
    // gates = [emb | h] @ [w_ih | w_hh]^T + b_ih + b_hh
    gemm_nt_kernel<<<dim3(4 * H / BNN, B / BMM), 256, 0, stream>>>(
        embbuf, E, hbuf, H, wih, E, whh, H, E, E + H, bih, bhh, glbuf, 4 * H, nullptr);
    // LSTM cell update
    lstm_cell_kernel<<<dim3(H / 256, B), 256, 0, stream>>>(glbuf, cbuf, hbuf, H);
    // logits = h @ lp_w^T + lp_b
    gemm_nt_kernel<<<dim3(V / BNN, B / BMM), 256, 0, stream>>>(
        hbuf, H, hbuf, H, lpw, H, lpw, H, H, H, lpb, nullptr, glbuf, V, nullptr);
    // log_softmax + gumbel + relaxed sample + straight-through write
    sample_kernel<<<B, 256, 0, stream>>>(glbuf, out, token, scale, s, Tp1, V, B);
  }
}

// Round 3
// 5451.516 us; speedup vs baseline: 2.3126x; 2.3126x over previous
//
#include <hip/hip_runtime.h>
#include <math.h>

// ---------------------------------------------------------------------------
// Sender: LSTM + RelaxedOneHotCategorical straight-through decode, 32 steps.
// Round 3: GEMMs moved to f16 MFMA with 2-way f16 split emulation of fp32
// (a = a0 + 2^-12 a1; 3 MFMA products, 2 accumulators; products are exact,
// residual ~2^-24 — same error class as fp32). h0 GEMM stays fp32 (one-time).
// ---------------------------------------------------------------------------

typedef _Float16 f16;
typedef f16 f16x8 __attribute__((ext_vector_type(8)));
typedef float f32x4 __attribute__((ext_vector_type(4)));

#define F16_MIN_NORM 6.104e-5f

// split v (fp32) into f16 pair: v ~= (float)h + (float)l * 2^-12.
// clamp h to 0 below f16-min-normal so MFMA denormal handling can't bite.
__device__ __forceinline__ void split_f16(float v, f16& h, f16& l) {
  f16 h0 = (fabsf(v) < F16_MIN_NORM) ? (f16)0.0f : (f16)v;
  float r = (v - (float)h0) * 4096.0f;   // exact subtract, exact scale
  h = h0; l = (f16)r;
}

// ------------------------- fp32 NT GEMM (h0 only) --------------------------
#define BMM 128
#define BNN 128
#define BKK 8
#define TM 8
#define TN 8

__global__ __launch_bounds__(256) void gemm_nt_kernel(
    const float* __restrict__ A, int lda,
    const float* __restrict__ B, int ldb, int K,
    const float* __restrict__ bias0,
    float* __restrict__ C, int ldc,
    float* __restrict__ czero)
{
  __shared__ float As[BKK][BMM];
  __shared__ float Bs[BKK][BNN];
  const int tid = threadIdx.x;
  const int bm = blockIdx.y * BMM;
  const int bn = blockIdx.x * BNN;
  const int tx = tid & 15;
  const int ty = tid >> 4;
  const int lrow = tid >> 1;
  const int lcol = (tid & 1) * 4;

  float acc[TM][TN];
#pragma unroll
  for (int i = 0; i < TM; ++i)
#pragma unroll
    for (int j = 0; j < TN; ++j) acc[i][j] = 0.0f;

  for (int kg = 0; kg < K; kg += BKK) {
    const float4 av = *(const float4*)(A + (size_t)(bm + lrow) * lda + kg + lcol);
    const float4 bv = *(const float4*)(B + (size_t)(bn + lrow) * ldb + kg + lcol);
    __syncthreads();
    As[lcol + 0][lrow] = av.x; As[lcol + 1][lrow] = av.y;
    As[lcol + 2][lrow] = av.z; As[lcol + 3][lrow] = av.w;
    Bs[lcol + 0][lrow] = bv.x; Bs[lcol + 1][lrow] = bv.y;
    Bs[lcol + 2][lrow] = bv.z; Bs[lcol + 3][lrow] = bv.w;
    __syncthreads();
#pragma unroll
    for (int k = 0; k < BKK; ++k) {
      float a[TM], bb[TN];
#pragma unroll
      for (int i = 0; i < TM; ++i) a[i] = As[k][ty * TM + i];
#pragma unroll
      for (int j = 0; j < TN; ++j) bb[j] = Bs[k][tx * TN + j];
#pragma unroll
      for (int i = 0; i < TM; ++i)
#pragma unroll
        for (int j = 0; j < TN; ++j)
          acc[i][j] = fmaf(a[i], bb[j], acc[i][j]);
    }
  }

#pragma unroll
  for (int i = 0; i < TM; ++i) {
    const int row = bm + ty * TM + i;
#pragma unroll
    for (int j = 0; j < TN; ++j) {
      const int col = bn + tx * TN + j;
      C[(size_t)row * ldc + col] = acc[i][j] + bias0[col];
      if (czero) czero[(size_t)row * ldc + col] = 0.0f;
    }
  }
}

// --------------------- f16-split MFMA GEMM (main engine) -------------------
// C[m,n] = sum_k A[m,k]*Bt[n,k] (+bias0[n] (+bias1[n])), A/Bt given as f16
// hi/lo plane pairs, with a 2-region K (concat) like the fp32 version.
// Block tile 128x128, BK=32, 4 waves each doing a 64x64 register tile.

#define GBK 32

#define GLOAD_LDS16(gsrc, ldst)                                               \
  __builtin_amdgcn_global_load_lds(                                           \
      (const __attribute__((address_space(1))) unsigned int*)(const void*)(gsrc), \
      (__attribute__((address_space(3))) unsigned int*)(void*)(ldst), 16, 0, 0)

__global__ __launch_bounds__(256, 1) void gemm_f16split(
    const f16* __restrict__ A00, const f16* __restrict__ A01, int lda0,
    const f16* __restrict__ A10, const f16* __restrict__ A11, int lda1,
    const f16* __restrict__ B00, const f16* __restrict__ B01, int ldb0,
    const f16* __restrict__ B10, const f16* __restrict__ B11, int ldb1,
    int Ksplit, int K,
    const float* __restrict__ bias0, const float* __restrict__ bias1,
    float* __restrict__ C, int ldc)
{
  __shared__ f16 lds[4][128][GBK];   // planes: A-hi, A-lo, B-hi, B-lo (32 KB)
  const int tid  = threadIdx.x;
  const int lane = tid & 63;
  const int wid  = tid >> 6;          // 4 waves
  const int bm   = blockIdx.y * 128;
  const int bn   = blockIdx.x * 128;
  const int wm   = (wid & 1) * 64;    // wave's 64x64 quadrant
  const int wn   = (wid >> 1) * 64;
  const int fr   = lane & 15;         // fragment row (m or n within 16-tile)
  const int fk   = (lane >> 4) * 8;   // fragment k offset (f16 units)

  // staging: wave `wid` stages plane `wid` (16B/lane, 16 rows/instr)
  const int  srow  = lane >> 2;       // row within 16-row group
  const int  scol  = (lane & 3) * 8;  // f16 col offset within BK
  const bool isA   = (wid < 2);
  const bool isLo  = (wid & 1);
  const int  rbase = isA ? bm : bn;

  f32x4 acc0[4][4], acc1[4][4];
#pragma unroll
  for (int i = 0; i < 4; ++i)
#pragma unroll
    for (int j = 0; j < 4; ++j) {
      acc0[i][j] = (f32x4)0.0f;
      acc1[i][j] = (f32x4)0.0f;
    }

  for (int kk = 0; kk < K; kk += GBK) {
    const f16* src; int ld, ke;
    if (kk < Ksplit) {
      ld = isA ? lda0 : ldb0; ke = kk;
      src = isA ? (isLo ? A01 : A00) : (isLo ? B01 : B00);
    } else {
      ld = isA ? lda1 : ldb1; ke = kk - Ksplit;
      src = isA ? (isLo ? A11 : A10) : (isLo ? B11 : B10);
    }
    __syncthreads();   // all frag reads of previous slice consumed
#pragma unroll
    for (int s = 0; s < 8; ++s) {
      const f16* g = src + (size_t)(rbase + s * 16 + srow) * ld + ke + scol;
      GLOAD_LDS16(g, &lds[wid][s * 16][0]);
    }
    __syncthreads();   // compiler drains vmcnt before barrier

    f16x8 a0[4], a1[4], b0[4], b1[4];
#pragma unroll
    for (int i = 0; i < 4; ++i) {
      a0[i] = *(const f16x8*)&lds[0][wm + i * 16 + fr][fk];
      a1[i] = *(const f16x8*)&lds[1][wm + i * 16 + fr][fk];
      b0[i] = *(const f16x8*)&lds[2][wn + i * 16 + fr][fk];
      b1[i] = *(const f16x8*)&lds[3][wn + i * 16 + fr][fk];
    }
#pragma unroll
    for (int i = 0; i < 4; ++i)
#pragma unroll
      for (int j = 0; j < 4; ++j) {
        acc0[i][j] = __builtin_amdgcn_mfma_f32_16x16x32_f16(a0[i], b0[j], acc0[i][j], 0, 0, 0);
        acc1[i][j] = __builtin_amdgcn_mfma_f32_16x16x32_f16(a0[i], b1[j], acc1[i][j], 0, 0, 0);
        acc1[i][j] = __builtin_amdgcn_mfma_f32_16x16x32_f16(a1[i], b0[j], acc1[i][j], 0, 0, 0);
      }
  }

  // epilogue: C = acc0 + acc1*2^-12 + biases.  D layout: col=lane&15,
  // row=(lane>>4)*4+r (verified m89).
  const bool has1 = (bias1 != nullptr);
  const int  q4   = (lane >> 4) * 4;
  const float s12 = 1.0f / 4096.0f;
#pragma unroll
  for (int j = 0; j < 4; ++j) {
    const int col = bn + wn + j * 16 + fr;
    const float bb0 = bias0[col];
    const float bb1 = has1 ? bias1[col] : 0.0f;
#pragma unroll
    for (int i = 0; i < 4; ++i) {
      const int rowb = bm + wm + i * 16 + q4;
#pragma unroll
      for (int r = 0; r < 4; ++r) {
        float v = acc0[i][j][r] + acc1[i][j][r] * s12;
        v = v + bb0;
        if (has1) v = v + bb1;
        C[(size_t)(rowb + r) * ldc + col] = v;
      }
    }
  }
}

// --------------------------- threefry / gumbel -----------------------------

__device__ __forceinline__ unsigned tf_rotl(unsigned x, int r) {
  return (x << r) | (x >> (32 - r));
}

// JAX threefry2x32-20, key = (0, 42), partitionable: draw = x0_out ^ x1_out.
__device__ inline float gumbel_at(unsigned idx) {
  const unsigned ks0 = 0u;
  const unsigned ks1 = 42u;
  const unsigned ks2 = 0x1BD11BDAu ^ ks0 ^ ks1;
  unsigned x0 = 0u + ks0;
  unsigned x1 = idx + ks1;
#define TFR(rot) { x0 += x1; x1 = tf_rotl(x1, rot); x1 ^= x0; }
  TFR(13) TFR(15) TFR(26) TFR(6)
  x0 += ks1; x1 += ks2 + 1u;
  TFR(17) TFR(29) TFR(16) TFR(24)
  x0 += ks2; x1 += ks0 + 2u;
  TFR(13) TFR(15) TFR(26) TFR(6)
  x0 += ks0; x1 += ks1 + 3u;
  TFR(17) TFR(29) TFR(16) TFR(24)
  x0 += ks1; x1 += ks2 + 4u;
  TFR(13) TFR(15) TFR(26) TFR(6)
  x0 += ks2; x1 += ks0 + 5u;
#undef TFR
  const unsigned bits = x0 ^ x1;
  const float f = __uint_as_float((bits >> 9) | 0x3F800000u) - 1.0f;
  const float tiny = 1.17549435082228751e-38f;
  const float u = fmaxf(tiny, f * (1.0f - tiny) + tiny);
  return -logf(-logf(u));
}

// ------------------------------ small kernels ------------------------------

__global__ void init_out0_kernel(float* __restrict__ out, int* __restrict__ token,
                                 float* __restrict__ scale,
                                 const int* __restrict__ startp, int Tp1, int V) {
  const int b = blockIdx.x;
  const int start = *startp;
  const size_t base = (size_t)b * Tp1 * V;
  for (int v = threadIdx.x; v < V; v += blockDim.x)
    out[base + v] = (v == start) ? 1.0f : 0.0f;
  if (threadIdx.x == 0) { token[b] = start; scale[b] = 1.0f; }
}

// elementwise fp32 -> f16 hi/lo planes
__global__ void split_kernel(const float* __restrict__ in,
                             f16* __restrict__ o0, f16* __restrict__ o1, int n) {
  const int i = blockIdx.x * blockDim.x + threadIdx.x;
  if (i < n) { f16 h, l; split_f16(in[i], h, l); o0[i] = h; o1[i] = l; }
}

__global__ void gather_emb_kernel(const float* __restrict__ emb,
                                  const int* __restrict__ token,
                                  const float* __restrict__ scale,
                                  f16* __restrict__ e0, f16* __restrict__ e1, int E) {
  const int b = blockIdx.x;
  const int e = threadIdx.x;            // blockDim.x == E
  const float v = scale[b] * emb[(size_t)token[b] * E + e];
  f16 h, l; split_f16(v, h, l);
  e0[(size_t)b * E + e] = h;
  e1[(size_t)b * E + e] = l;
}

__device__ __forceinline__ float sigm(float x) { return 1.0f / (1.0f + expf(-x)); }

__global__ void lstm_cell_kernel(const float* __restrict__ gates,
                                 float* __restrict__ cbuf,
                                 f16* __restrict__ h0p, f16* __restrict__ h1p, int H) {
  const int n = blockIdx.x * blockDim.x + threadIdx.x;
  const int b = blockIdx.y;
  const size_t gbase = (size_t)b * 4 * H;
  const float gi = gates[gbase + n];
  const float gf = gates[gbase + H + n];
  const float gg = gates[gbase + 2 * H + n];
  const float go = gates[gbase + 3 * H + n];
  const size_t off = (size_t)b * H + n;
  const float c = cbuf[off];
  const float cn = __fadd_rn(__fmul_rn(sigm(gf), c), __fmul_rn(sigm(gi), tanhf(gg)));
  const float hn = __fmul_rn(sigm(go), tanhf(cn));
  cbuf[off] = cn;
  f16 h, l; split_f16(hn, h, l);
  h0p[off] = h; h1p[off] = l;
}

// One block (256 thr) per batch row; V = 4096 (16 elems/thread).
__global__ __launch_bounds__(256) void sample_kernel(
    const float* __restrict__ logits, float* __restrict__ out,
    int* __restrict__ token, float* __restrict__ scale,
    int step, int Tp1, int V, int B)
{
  const int b = blockIdx.x;
  const int tid = threadIdx.x;
  const int lane = tid & 63, wv = tid >> 6;
  __shared__ float sh_m[4], sh_se[4], sh_zm[4], sh_s2[4], sh_av[4];
  __shared__ int sh_ai[4];

  const float* lrow = logits + (size_t)b * V;
  float l[16];
#pragma unroll
  for (int j = 0; j < 16; ++j) l[j] = lrow[tid + 256 * j];

  float m = -INFINITY;
#pragma unroll
  for (int j = 0; j < 16; ++j) m = fmaxf(m, l[j]);
  for (int o = 32; o > 0; o >>= 1) m = fmaxf(m, __shfl_down(m, o, 64));
  if (lane == 0) sh_m[wv] = m;
  __syncthreads();
  m = fmaxf(fmaxf(sh_m[0], sh_m[1]), fmaxf(sh_m[2], sh_m[3]));

  float se = 0.f;
#pragma unroll
  for (int j = 0; j < 16; ++j) { l[j] = l[j] - m; se += expf(l[j]); }
  for (int o = 32; o > 0; o >>= 1) se += __shfl_down(se, o, 64);
  if (lane == 0) sh_se[wv] = se;
  __syncthreads();
  se = ((sh_se[0] + sh_se[1]) + sh_se[2]) + sh_se[3];
  const float lse = logf(se);

  const unsigned ibase = ((unsigned)step * (unsigned)B + (unsigned)b) * (unsigned)V;
#pragma unroll
  for (int j = 0; j < 16; ++j) {
    const unsigned v = (unsigned)(tid + 256 * j);
    const float g = gumbel_at(ibase + v);
    l[j] = ((l[j] - lse) + g) / 1.2f;
  }

  float zm = -INFINITY;
#pragma unroll
  for (int j = 0; j < 16; ++j) zm = fmaxf(zm, l[j]);
  for (int o = 32; o > 0; o >>= 1) zm = fmaxf(zm, __shfl_down(zm, o, 64));
  if (lane == 0) sh_zm[wv] = zm;
  __syncthreads();
  zm = fmaxf(fmaxf(sh_zm[0], sh_zm[1]), fmaxf(sh_zm[2], sh_zm[3]));

  float s2 = 0.f;
#pragma unroll
  for (int j = 0; j < 16; ++j) { l[j] = expf(l[j] - zm); s2 += l[j]; }
  for (int o = 32; o > 0; o >>= 1) s2 += __shfl_down(s2, o, 64);
  if (lane == 0) sh_s2[wv] = s2;
  __syncthreads();
  s2 = ((sh_s2[0] + sh_s2[1]) + sh_s2[2]) + sh_s2[3];

  float bv = -INFINITY; int bi = 0x7fffffff;
#pragma unroll
  for (int j = 0; j < 16; ++j) {
    const float y = l[j] / s2;
    const int v = tid + 256 * j;
    if (y > bv || (y == bv && v < bi)) { bv = y; bi = v; }
  }
  for (int o = 32; o > 0; o >>= 1) {
    const float ov = __shfl_down(bv, o, 64);
    const int oi = __shfl_down(bi, o, 64);
    if (ov > bv || (ov == bv && oi < bi)) { bv = ov; bi = oi; }
  }
  if (lane == 0) { sh_av[wv] = bv; sh_ai[wv] = bi; }
  __syncthreads();
  bv = sh_av[0]; bi = sh_ai[0];
#pragma unroll
  for (int w = 1; w < 4; ++w) {
    const float ov = sh_av[w]; const int oi = sh_ai[w];
    if (ov > bv || (ov == bv && oi < bi)) { bv = ov; bi = oi; }
  }

  const float sc = (1.0f - bv) + bv;
  float* orow = out + ((size_t)b * Tp1 + (step + 1)) * V;
#pragma unroll
  for (int j = 0; j < 16; ++j) {
    const int v = tid + 256 * j;
    orow[v] = (v == bi) ? sc : 0.0f;
  }
  if (tid == 0) { token[b] = bi; scale[b] = sc; }
}

// ------------------------------- host side ---------------------------------

extern "C" void kernel_launch(void* const* d_in, const int* in_sizes, int n_in,
                              void* d_out, int out_size, void* d_ws, size_t ws_size,
                              hipStream_t stream) {
  const float* t     = (const float*)d_in[0];
  const float* emb   = (const float*)d_in[1];
  const float* affw  = (const float*)d_in[2];
  const float* affb  = (const float*)d_in[3];
  const float* wih   = (const float*)d_in[4];
  const float* whh   = (const float*)d_in[5];
  const float* bih   = (const float*)d_in[6];
  const float* bhh   = (const float*)d_in[7];
  const float* lpw   = (const float*)d_in[8];
  const float* lpb   = (const float*)d_in[9];
  const int*   start = (const int*)d_in[10];
  float* out = (float*)d_out;

  const int H = in_sizes[3];             // 1024
  const int V = in_sizes[9];             // 4096
  const int E = in_sizes[1] / V;         // 256
  const int F = in_sizes[2] / H;         // 2048
  const int B = in_sizes[0] / F;         // 1024
  const int Tp1 = out_size / (B * V);    // 33
  const int T = Tp1 - 1;                 // 32

  // ---- workspace layout (bytes; ~65 MB total) ----
  char* p = (char*)d_ws;
  float* cbuf  = (float*)p; p += (size_t)B * H * 4;         // 4 MB
  float* glbuf = (float*)p; p += (size_t)B * 4 * H * 4;     // 16 MB (gates/logits)
  float* hbuf  = (float*)p; p += (size_t)B * H * 4;         // 4 MB (h0 only)
  f16* wihA0 = (f16*)p; p += (size_t)4 * H * E * 2;
  f16* wihA1 = (f16*)p; p += (size_t)4 * H * E * 2;
  f16* whhA0 = (f16*)p; p += (size_t)4 * H * H * 2;
  f16* whhA1 = (f16*)p; p += (size_t)4 * H * H * 2;
  f16* lpwA0 = (f16*)p; p += (size_t)V * H * 2;
  f16* lpwA1 = (f16*)p; p += (size_t)V * H * 2;
  f16* embA0 = (f16*)p; p += (size_t)B * E * 2;
  f16* embA1 = (f16*)p; p += (size_t)B * E * 2;
  f16* hA0   = (f16*)p; p += (size_t)B * H * 2;
  f16* hA1   = (f16*)p; p += (size_t)B * H * 2;
  int*   token = (int*)p; p += (size_t)B * 4;
  float* scale = (float*)p; p += (size_t)B * 4;
  (void)ws_size; (void)n_in;

  // init out slice 0 + token/scale
  init_out0_kernel<<<B, 256, 0, stream>>>(out, token, scale, start, Tp1, V);

  // pre-split the recurrent weights into f16 hi/lo planes (once per call)
  split_kernel<<<(4 * H * E + 255) / 256, 256, 0, stream>>>(wih, wihA0, wihA1, 4 * H * E);
  split_kernel<<<(4 * H * H + 255) / 256, 256, 0, stream>>>(whh, whhA0, whhA1, 4 * H * H);
  split_kernel<<<(V * H + 255) / 256, 256, 0, stream>>>(lpw, lpwA0, lpwA1, V * H);

  // h0 = t @ aff_w.T + aff_b (fp32, one-time); zero cbuf; then split h0
  gemm_nt_kernel<<<dim3(H / BNN, B / BMM), 256, 0, stream>>>(
      t, F, affw, F, F, affb, hbuf, H, cbuf);
  split_kernel<<<(B * H + 255) / 256, 256, 0, stream>>>(hbuf, hA0, hA1, B * H);

  for (int s = 0; s < T; ++s) {
    gather_emb_kernel<<<B, E, 0, stream>>>(emb, token, scale, embA0, embA1, E);
    // gates = [emb | h] @ [w_ih | w_hh]^T + b_ih + b_hh   (K = E + H)
    gemm_f16split<<<dim3(4 * H / 128, B / 128), 256, 0, stream>>>(
        embA0, embA1, E, hA0, hA1, H,
        wihA0, wihA1, E, whhA0, whhA1, H,
        E, E + H, bih, bhh, glbuf, 4 * H);
    lstm_cell_kernel<<<dim3(H / 256, B), 256, 0, stream>>>(glbuf, cbuf, hA0, hA1, H);
    // logits = h @ lp_w^T + lp_b   (single K region)
    gemm_f16split<<<dim3(V / 128, B / 128), 256, 0, stream>>>(
        hA0, hA1, H, hA0, hA1, H,
        lpwA0, lpwA1, H, lpwA0, lpwA1, H,
        H, H, lpb, nullptr, glbuf, V);
    sample_kernel<<<B, 256, 0, stream>>>(glbuf, out, token, scale, s, Tp1, V, B);
  }
}

// Round 4
// 4859.367 us; speedup vs baseline: 2.5944x; 1.1219x over previous
//
#include <hip/hip_runtime.h>
#include <math.h>

// ---------------------------------------------------------------------------
// Sender: LSTM + Gumbel straight-through decode, 32 steps.
// Round 4: 3 kernels/step.
//  A: gates GEMM (f16-split MFMA, packed gate-interleaved weights) + fused
//     LSTM cell epilogue -> h (double-buffered), c.
//  B: logits GEMM + fused sampling partials (w = logit + gumbel; per-64col
//     max/argmax/sumexp).
//  C: finalize: reduce partials -> token/scale, write one-hot row, produce
//     next-step scaled+split embedding.
// GEMMs: 512 thr / 8 waves, in-block split-K (2 groups), 64KB LDS, 64x64
// wave tiles, 3-product f16-split (exact products, ~2^-24 residual).
// ---------------------------------------------------------------------------

typedef _Float16 f16;
typedef f16 f16x8 __attribute__((ext_vector_type(8)));
typedef float f32x4 __attribute__((ext_vector_type(4)));

#define F16_MIN_NORM 6.104e-5f

__device__ __forceinline__ void split_f16(float v, f16& h, f16& l) {
  f16 h0 = (fabsf(v) < F16_MIN_NORM) ? (f16)0.0f : (f16)v;
  float r = (v - (float)h0) * 4096.0f;
  h = h0; l = (f16)r;
}

__device__ __forceinline__ float sigm(float x) { return 1.0f / (1.0f + expf(-x)); }

#define GLOAD_LDS16(gsrc, ldst)                                               \
  __builtin_amdgcn_global_load_lds(                                           \
      (const __attribute__((address_space(1))) unsigned int*)(const void*)(gsrc), \
      (__attribute__((address_space(3))) unsigned int*)(void*)(ldst), 16, 0, 0)

// --------------------------- threefry / gumbel -----------------------------

__device__ __forceinline__ unsigned tf_rotl(unsigned x, int r) {
  return (x << r) | (x >> (32 - r));
}

// JAX threefry2x32-20, key (0,42), partitionable: draw = x0_out ^ x1_out.
__device__ inline float gumbel_at(unsigned idx) {
  const unsigned ks0 = 0u;
  const unsigned ks1 = 42u;
  const unsigned ks2 = 0x1BD11BDAu ^ ks0 ^ ks1;
  unsigned x0 = 0u + ks0;
  unsigned x1 = idx + ks1;
#define TFR(rot) { x0 += x1; x1 = tf_rotl(x1, rot); x1 ^= x0; }
  TFR(13) TFR(15) TFR(26) TFR(6)
  x0 += ks1; x1 += ks2 + 1u;
  TFR(17) TFR(29) TFR(16) TFR(24)
  x0 += ks2; x1 += ks0 + 2u;
  TFR(13) TFR(15) TFR(26) TFR(6)
  x0 += ks0; x1 += ks1 + 3u;
  TFR(17) TFR(29) TFR(16) TFR(24)
  x0 += ks1; x1 += ks2 + 4u;
  TFR(13) TFR(15) TFR(26) TFR(6)
  x0 += ks2; x1 += ks0 + 5u;
#undef TFR
  const unsigned bits = x0 ^ x1;
  const float f = __uint_as_float((bits >> 9) | 0x3F800000u) - 1.0f;
  const float tiny = 1.17549435082228751e-38f;
  const float u = fmaxf(tiny, f * (1.0f - tiny) + tiny);
  return -logf(-logf(u));
}

// ------------------------- setup / pack kernels ----------------------------

// one-hot start row into out[:,0,:] + split embedding of start token
__global__ void init_kernel(float* __restrict__ out, const float* __restrict__ emb,
                            f16* __restrict__ e0, f16* __restrict__ e1,
                            const int* __restrict__ startp, int Tp1, int V, int E) {
  const int b = blockIdx.x;
  const int start = *startp;
  float* orow = out + (size_t)b * Tp1 * V;
  for (int v = threadIdx.x; v < V; v += blockDim.x)
    orow[v] = (v == start) ? 1.0f : 0.0f;
  if (threadIdx.x < E) {
    const float v = emb[(size_t)start * E + threadIdx.x];
    f16 h, l; split_f16(v, h, l);
    e0[(size_t)b * E + threadIdx.x] = h;
    e1[(size_t)b * E + threadIdx.x] = l;
  }
}

// packed gate col p: gate q=(p>>4)&3, unit u=((p>>6)<<4)+(p&15); orig row
// n' = q*H + u. wpk[p][k] = k<E ? wih[n'][k] : whh[n'][k-E], split.
__global__ void pack_gates_kernel(const float* __restrict__ wih,
                                  const float* __restrict__ whh,
                                  f16* __restrict__ w0, f16* __restrict__ w1,
                                  int E, int H, int K) {
  const int k = blockIdx.x * blockDim.x + threadIdx.x;   // [0,K)
  const int p = blockIdx.y;
  if (k >= K) return;
  const int n = ((p >> 4) & 3) * H + ((p >> 6) << 4) + (p & 15);
  const float v = (k < E) ? wih[(size_t)n * E + k] : whh[(size_t)n * H + (k - E)];
  f16 h, l; split_f16(v, h, l);
  w0[(size_t)p * K + k] = h;
  w1[(size_t)p * K + k] = l;
}

__global__ void pack_bias_kernel(const float* __restrict__ bih,
                                 const float* __restrict__ bhh,
                                 float* __restrict__ bi, float* __restrict__ bh, int H) {
  const int p = blockIdx.x * blockDim.x + threadIdx.x;
  const int n = ((p >> 4) & 3) * H + ((p >> 6) << 4) + (p & 15);
  bi[p] = bih[n];
  bh[p] = bhh[n];
}

__global__ void split_kernel(const float* __restrict__ in,
                             f16* __restrict__ o0, f16* __restrict__ o1, int n) {
  const int i = blockIdx.x * blockDim.x + threadIdx.x;
  if (i < n) { f16 h, l; split_f16(in[i], h, l); o0[i] = h; o1[i] = l; }
}

// -------------------- fp32 NT GEMM for h0 (one-time) -----------------------
__global__ __launch_bounds__(256) void gemm_h0_kernel(
    const float* __restrict__ A, int lda,
    const float* __restrict__ B, int ldb, int K,
    const float* __restrict__ bias0,
    f16* __restrict__ h0p, f16* __restrict__ h1p, int ldc,
    float* __restrict__ czero)
{
  __shared__ float As[8][128];
  __shared__ float Bs[8][128];
  const int tid = threadIdx.x;
  const int bm = blockIdx.y * 128;
  const int bn = blockIdx.x * 128;
  const int tx = tid & 15;
  const int ty = tid >> 4;
  const int lrow = tid >> 1;
  const int lcol = (tid & 1) * 4;

  float acc[8][8];
#pragma unroll
  for (int i = 0; i < 8; ++i)
#pragma unroll
    for (int j = 0; j < 8; ++j) acc[i][j] = 0.0f;

  for (int kg = 0; kg < K; kg += 8) {
    const float4 av = *(const float4*)(A + (size_t)(bm + lrow) * lda + kg + lcol);
    const float4 bv = *(const float4*)(B + (size_t)(bn + lrow) * ldb + kg + lcol);
    __syncthreads();
    As[lcol + 0][lrow] = av.x; As[lcol + 1][lrow] = av.y;
    As[lcol + 2][lrow] = av.z; As[lcol + 3][lrow] = av.w;
    Bs[lcol + 0][lrow] = bv.x; Bs[lcol + 1][lrow] = bv.y;
    Bs[lcol + 2][lrow] = bv.z; Bs[lcol + 3][lrow] = bv.w;
    __syncthreads();
#pragma unroll
    for (int k = 0; k < 8; ++k) {
      float a[8], bb[8];
#pragma unroll
      for (int i = 0; i < 8; ++i) a[i] = As[k][ty * 8 + i];
#pragma unroll
      for (int j = 0; j < 8; ++j) bb[j] = Bs[k][tx * 8 + j];
#pragma unroll
      for (int i = 0; i < 8; ++i)
#pragma unroll
        for (int j = 0; j < 8; ++j)
          acc[i][j] = fmaf(a[i], bb[j], acc[i][j]);
    }
  }

#pragma unroll
  for (int i = 0; i < 8; ++i) {
    const int row = bm + ty * 8 + i;
#pragma unroll
    for (int j = 0; j < 8; ++j) {
      const int col = bn + tx * 8 + j;
      const float v = acc[i][j] + bias0[col];
      f16 h, l; split_f16(v, h, l);
      h0p[(size_t)row * ldc + col] = h;
      h1p[(size_t)row * ldc + col] = l;
      czero[(size_t)row * ldc + col] = 0.0f;
    }
  }
}

// ---------------- Kernel A: gates GEMM + fused LSTM cell -------------------
// C[128 rows(batch) x 128 cols(packed gates)], K two-region (emb E | h H).
// 8 waves: group g=wid>>2 handles K half; wave quadrant 64x64.
__global__ __launch_bounds__(512, 2) void gates_kernel(
    const f16* __restrict__ e0, const f16* __restrict__ e1, int E,
    const f16* __restrict__ hin0, const f16* __restrict__ hin1, int H,
    const f16* __restrict__ w0, const f16* __restrict__ w1, int K,
    const float* __restrict__ bi, const float* __restrict__ bh,
    float* __restrict__ cbuf,
    f16* __restrict__ hout0, f16* __restrict__ hout1)
{
  __shared__ f16 lds[2][4][128][32];   // 64 KB
  const int tid  = threadIdx.x;
  const int lane = tid & 63;
  const int wid  = tid >> 6;
  const int g    = wid >> 2;
  const int pid  = wid & 3;            // plane staged by this wave
  const int bm   = blockIdx.y * 128;
  const int bn   = blockIdx.x * 128;
  const int wm   = (wid & 1) * 64;
  const int wn   = ((wid >> 1) & 1) * 64;
  const int fr   = lane & 15;
  const int fk   = (lane >> 4) * 8;
  const int srow = lane >> 2;
  const int scol = (lane & 3) * 8;
  const bool isA = (pid < 2);
  const bool isLo = (pid & 1);
  const int Khalf = K / 2;
  const int NS = Khalf / 32;

  f32x4 acc0[4][4], acc1[4][4];
#pragma unroll
  for (int i = 0; i < 4; ++i)
#pragma unroll
    for (int j = 0; j < 4; ++j) { acc0[i][j] = (f32x4)0.0f; acc1[i][j] = (f32x4)0.0f; }

  for (int it = 0; it < NS; ++it) {
    const int kk = g * Khalf + it * 32;
    const f16* src; int ld, ke, rbase;
    if (isA) {
      rbase = bm;
      if (kk < E) { src = isLo ? e1 : e0; ld = E; ke = kk; }
      else        { src = isLo ? hin1 : hin0; ld = H; ke = kk - E; }
    } else {
      rbase = bn; src = isLo ? w1 : w0; ld = K; ke = kk;
    }
    __syncthreads();
#pragma unroll
    for (int s = 0; s < 8; ++s) {
      const f16* gp = src + (size_t)(rbase + s * 16 + srow) * ld + ke + scol;
      GLOAD_LDS16(gp, &lds[g][pid][s * 16][0]);
    }
    __syncthreads();

    f16x8 a0[4], a1[4], b0[4], b1[4];
#pragma unroll
    for (int i = 0; i < 4; ++i) {
      a0[i] = *(const f16x8*)&lds[g][0][wm + i * 16 + fr][fk];
      a1[i] = *(const f16x8*)&lds[g][1][wm + i * 16 + fr][fk];
      b0[i] = *(const f16x8*)&lds[g][2][wn + i * 16 + fr][fk];
      b1[i] = *(const f16x8*)&lds[g][3][wn + i * 16 + fr][fk];
    }
#pragma unroll
    for (int i = 0; i < 4; ++i)
#pragma unroll
      for (int j = 0; j < 4; ++j) {
        acc0[i][j] = __builtin_amdgcn_mfma_f32_16x16x32_f16(a0[i], b0[j], acc0[i][j], 0, 0, 0);
        acc1[i][j] = __builtin_amdgcn_mfma_f32_16x16x32_f16(a0[i], b1[j], acc1[i][j], 0, 0, 0);
        acc1[i][j] = __builtin_amdgcn_mfma_f32_16x16x32_f16(a1[i], b0[j], acc1[i][j], 0, 0, 0);
      }
  }

  // cross-group combine through LDS
  float* cmb = (float*)&lds[0][0][0][0];   // 16384 floats
  const float s12 = 1.0f / 4096.0f;
  __syncthreads();
  if (g == 1) {
#pragma unroll
    for (int i = 0; i < 4; ++i)
#pragma unroll
      for (int j = 0; j < 4; ++j)
#pragma unroll
        for (int r = 0; r < 4; ++r)
          cmb[pid * 4096 + ((i * 4 + j) * 4 + r) * 64 + lane] =
              acc0[i][j][r] + acc1[i][j][r] * s12;
  }
  __syncthreads();
  if (g == 1) return;

  // epilogue (waves 0..3 cover the full 128x128 tile)
  const int q4 = (lane >> 4) * 4;
  float biv[4], bhv[4];
#pragma unroll
  for (int j = 0; j < 4; ++j) {
    const int col = bn + wn + j * 16 + fr;
    biv[j] = bi[col]; bhv[j] = bh[col];
  }
  const int nunit = ((bn + wn) >> 2) + fr;   // hidden unit index
#pragma unroll
  for (int i = 0; i < 4; ++i) {
#pragma unroll
    for (int r = 0; r < 4; ++r) {
      const int row = bm + wm + i * 16 + q4 + r;
      float gv[4];
#pragma unroll
      for (int j = 0; j < 4; ++j) {
        const float other = cmb[pid * 4096 + ((i * 4 + j) * 4 + r) * 64 + lane];
        gv[j] = ((acc0[i][j][r] + acc1[i][j][r] * s12) + other + biv[j]) + bhv[j];
      }
      const size_t off = (size_t)row * H + nunit;
      const float c = cbuf[off];
      const float cn = __fadd_rn(__fmul_rn(sigm(gv[1]), c),
                                 __fmul_rn(sigm(gv[0]), tanhf(gv[2])));
      const float hn = __fmul_rn(sigm(gv[3]), tanhf(cn));
      cbuf[off] = cn;
      f16 hh, hl; split_f16(hn, hh, hl);
      hout0[off] = hh; hout1[off] = hl;
    }
  }
}

// ------------- Kernel B: logits GEMM + fused sampling partials -------------
// C[128 batch x 128 vocab], K = H single region. Partials per 64-col group:
// max(w), argmax col, sum exp((w - max)/1.2), w = logit + gumbel.
__global__ __launch_bounds__(512, 2) void logits_kernel(
    const f16* __restrict__ h0p, const f16* __restrict__ h1p, int H,
    const f16* __restrict__ w0, const f16* __restrict__ w1,
    const float* __restrict__ lpb,
    float* __restrict__ partM, float* __restrict__ partS, int* __restrict__ partI,
    int step, int B, int V)
{
  __shared__ f16 lds[2][4][128][32];
  const int tid  = threadIdx.x;
  const int lane = tid & 63;
  const int wid  = tid >> 6;
  const int g    = wid >> 2;
  const int pid  = wid & 3;
  const int bm   = blockIdx.y * 128;
  const int bn   = blockIdx.x * 128;
  const int wm   = (wid & 1) * 64;
  const int wn   = ((wid >> 1) & 1) * 64;
  const int fr   = lane & 15;
  const int fk   = (lane >> 4) * 8;
  const int srow = lane >> 2;
  const int scol = (lane & 3) * 8;
  const bool isA = (pid < 2);
  const bool isLo = (pid & 1);
  const int Khalf = H / 2;
  const int NS = Khalf / 32;

  f32x4 acc0[4][4], acc1[4][4];
#pragma unroll
  for (int i = 0; i < 4; ++i)
#pragma unroll
    for (int j = 0; j < 4; ++j) { acc0[i][j] = (f32x4)0.0f; acc1[i][j] = (f32x4)0.0f; }

  for (int it = 0; it < NS; ++it) {
    const int kk = g * Khalf + it * 32;
    const f16* src = isA ? (isLo ? h1p : h0p) : (isLo ? w1 : w0);
    const int rbase = isA ? bm : bn;
    __syncthreads();
#pragma unroll
    for (int s = 0; s < 8; ++s) {
      const f16* gp = src + (size_t)(rbase + s * 16 + srow) * H + kk + scol;
      GLOAD_LDS16(gp, &lds[g][pid][s * 16][0]);
    }
    __syncthreads();

    f16x8 a0[4], a1[4], b0[4], b1[4];
#pragma unroll
    for (int i = 0; i < 4; ++i) {
      a0[i] = *(const f16x8*)&lds[g][0][wm + i * 16 + fr][fk];
      a1[i] = *(const f16x8*)&lds[g][1][wm + i * 16 + fr][fk];
      b0[i] = *(const f16x8*)&lds[g][2][wn + i * 16 + fr][fk];
      b1[i] = *(const f16x8*)&lds[g][3][wn + i * 16 + fr][fk];
    }
#pragma unroll
    for (int i = 0; i < 4; ++i)
#pragma unroll
      for (int j = 0; j < 4; ++j) {
        acc0[i][j] = __builtin_amdgcn_mfma_f32_16x16x32_f16(a0[i], b0[j], acc0[i][j], 0, 0, 0);
        acc1[i][j] = __builtin_amdgcn_mfma_f32_16x16x32_f16(a0[i], b1[j], acc1[i][j], 0, 0, 0);
        acc1[i][j] = __builtin_amdgcn_mfma_f32_16x16x32_f16(a1[i], b0[j], acc1[i][j], 0, 0, 0);
      }
  }

  float* cmb = (float*)&lds[0][0][0][0];
  const float s12 = 1.0f / 4096.0f;
  __syncthreads();
  if (g == 1) {
#pragma unroll
    for (int i = 0; i < 4; ++i)
#pragma unroll
      for (int j = 0; j < 4; ++j)
#pragma unroll
        for (int r = 0; r < 4; ++r)
          cmb[pid * 4096 + ((i * 4 + j) * 4 + r) * 64 + lane] =
              acc0[i][j][r] + acc1[i][j][r] * s12;
  }
  __syncthreads();
  if (g == 1) return;

  // w = logit + gumbel (overwrite acc0)
  const int q4 = (lane >> 4) * 4;
  float bv[4];
#pragma unroll
  for (int j = 0; j < 4; ++j) bv[j] = lpb[bn + wn + j * 16 + fr];
#pragma unroll
  for (int i = 0; i < 4; ++i)
#pragma unroll
    for (int j = 0; j < 4; ++j) {
      const int col = bn + wn + j * 16 + fr;
#pragma unroll
      for (int r = 0; r < 4; ++r) {
        const int row = bm + wm + i * 16 + q4 + r;
        const float other = cmb[pid * 4096 + ((i * 4 + j) * 4 + r) * 64 + lane];
        const float logit = (acc0[i][j][r] + acc1[i][j][r] * s12) + other + bv[j];
        const unsigned gidx = ((unsigned)(step * B + row)) * (unsigned)V + (unsigned)col;
        acc0[i][j][r] = logit + gumbel_at(gidx);
      }
    }

  // per-row reduce over this wave's 64-col quadrant
  const int grp = (bn + wn) >> 6;
#pragma unroll
  for (int i = 0; i < 4; ++i) {
#pragma unroll
    for (int r = 0; r < 4; ++r) {
      float mx = -INFINITY; int ix = 0;
#pragma unroll
      for (int j = 0; j < 4; ++j) {
        const float w = acc0[i][j][r];
        const int col = bn + wn + j * 16 + fr;
        if (w > mx) { mx = w; ix = col; }
      }
#pragma unroll
      for (int m = 1; m < 16; m <<= 1) {
        const float om = __shfl_xor(mx, m, 64);
        const int oi = __shfl_xor(ix, m, 64);
        if (om > mx || (om == mx && oi < ix)) { mx = om; ix = oi; }
      }
      float s = 0.0f;
#pragma unroll
      for (int j = 0; j < 4; ++j) s += expf((acc0[i][j][r] - mx) / 1.2f);
#pragma unroll
      for (int m = 1; m < 16; m <<= 1) s += __shfl_xor(s, m, 64);
      if (fr == 0) {
        const int row = bm + wm + i * 16 + q4 + r;
        partM[(size_t)row * 64 + grp] = mx;
        partS[(size_t)row * 64 + grp] = s;
        partI[(size_t)row * 64 + grp] = ix;
      }
    }
  }
}

// ---------------- Kernel C: finalize + write + next embedding --------------
__global__ __launch_bounds__(256) void finalize_kernel(
    const float* __restrict__ partM, const float* __restrict__ partS,
    const int* __restrict__ partI,
    const float* __restrict__ emb,
    float* __restrict__ out,
    f16* __restrict__ e0, f16* __restrict__ e1,
    int step, int Tp1, int V, int E)
{
  const int b = blockIdx.x;
  const int tid = threadIdx.x;
  __shared__ float s_sc;
  __shared__ int s_tok;

  if (tid < 64) {
    const float m0 = partM[(size_t)b * 64 + tid];
    const float s0 = partS[(size_t)b * 64 + tid];
    const int i0 = partI[(size_t)b * 64 + tid];
    float mx = m0; int ix = i0;
#pragma unroll
    for (int m = 1; m < 64; m <<= 1) {
      const float om = __shfl_xor(mx, m, 64);
      const int oi = __shfl_xor(ix, m, 64);
      if (om > mx || (om == mx && oi < ix)) { mx = om; ix = oi; }
    }
    float c = s0 * expf((m0 - mx) / 1.2f);
#pragma unroll
    for (int m = 1; m < 64; m <<= 1) c += __shfl_xor(c, m, 64);
    if (tid == 0) {
      const float y = 1.0f / c;
      s_sc = (1.0f - y) + y;
      s_tok = ix;
    }
  }
  __syncthreads();
  const float sc = s_sc;
  const int tok = s_tok;

  float* orow = out + ((size_t)b * Tp1 + step + 1) * V;
  for (int v = tid; v < V; v += 256) orow[v] = (v == tok) ? sc : 0.0f;

  if (tid < E) {
    const float ev = sc * emb[(size_t)tok * E + tid];
    f16 h, l; split_f16(ev, h, l);
    e0[(size_t)b * E + tid] = h;
    e1[(size_t)b * E + tid] = l;
  }
}

// ------------------------------- host side ---------------------------------

extern "C" void kernel_launch(void* const* d_in, const int* in_sizes, int n_in,
                              void* d_out, int out_size, void* d_ws, size_t ws_size,
                              hipStream_t stream) {
  const float* t     = (const float*)d_in[0];
  const float* emb   = (const float*)d_in[1];
  const float* affw  = (const float*)d_in[2];
  const float* affb  = (const float*)d_in[3];
  const float* wih   = (const float*)d_in[4];
  const float* whh   = (const float*)d_in[5];
  const float* bih   = (const float*)d_in[6];
  const float* bhh   = (const float*)d_in[7];
  const float* lpw   = (const float*)d_in[8];
  const float* lpb   = (const float*)d_in[9];
  const int*   start = (const int*)d_in[10];
  float* out = (float*)d_out;

  const int H = in_sizes[3];             // 1024
  const int V = in_sizes[9];             // 4096
  const int E = in_sizes[1] / V;         // 256
  const int F = in_sizes[2] / H;         // 2048
  const int B = in_sizes[0] / F;         // 1024
  const int Tp1 = out_size / (B * V);    // 33
  const int T = Tp1 - 1;                 // 32
  const int KG = E + H;                  // 1280

  // ---- workspace layout ----
  char* p = (char*)d_ws;
  float* cbuf  = (float*)p; p += (size_t)B * H * 4;           // 4 MB
  f16* hA0[2]; f16* hA1[2];
  hA0[0] = (f16*)p; p += (size_t)B * H * 2;
  hA1[0] = (f16*)p; p += (size_t)B * H * 2;
  hA0[1] = (f16*)p; p += (size_t)B * H * 2;
  hA1[1] = (f16*)p; p += (size_t)B * H * 2;                   // 8 MB
  f16* embA0 = (f16*)p; p += (size_t)B * E * 2;
  f16* embA1 = (f16*)p; p += (size_t)B * E * 2;               // 1 MB
  f16* wg0 = (f16*)p; p += (size_t)V * KG * 2;                // 10 MB (packed gates)
  f16* wg1 = (f16*)p; p += (size_t)V * KG * 2;
  f16* wl0 = (f16*)p; p += (size_t)V * H * 2;                 // 8 MB (lp_w)
  f16* wl1 = (f16*)p; p += (size_t)V * H * 2;
  float* bgi = (float*)p; p += (size_t)V * 4;
  float* bgh = (float*)p; p += (size_t)V * 4;
  float* partM = (float*)p; p += (size_t)B * 64 * 4;
  float* partS = (float*)p; p += (size_t)B * 64 * 4;
  int*   partI = (int*)p;   p += (size_t)B * 64 * 4;
  (void)ws_size; (void)n_in;

  // ---- setup ----
  init_kernel<<<B, 256, 0, stream>>>(out, emb, embA0, embA1, start, Tp1, V, E);
  pack_gates_kernel<<<dim3((KG + 255) / 256, V), 256, 0, stream>>>(
      wih, whh, wg0, wg1, E, H, KG);
  pack_bias_kernel<<<V / 256, 256, 0, stream>>>(bih, bhh, bgi, bgh, H);
  split_kernel<<<(V * H + 255) / 256, 256, 0, stream>>>(lpw, wl0, wl1, V * H);
  // h0 = t @ aff_w.T + aff_b -> split into hA[0]; zero cbuf
  gemm_h0_kernel<<<dim3(H / 128, B / 128), 256, 0, stream>>>(
      t, F, affw, F, F, affb, hA0[0], hA1[0], H, cbuf);

  for (int s = 0; s < T; ++s) {
    const int cur = s & 1, nxt = (s + 1) & 1;
    gates_kernel<<<dim3(V / 128, B / 128), 512, 0, stream>>>(
        embA0, embA1, E, hA0[cur], hA1[cur], H,
        wg0, wg1, KG, bgi, bgh, cbuf, hA0[nxt], hA1[nxt]);
    logits_kernel<<<dim3(V / 128, B / 128), 512, 0, stream>>>(
        hA0[nxt], hA1[nxt], H, wl0, wl1, lpb,
        partM, partS, partI, s, B, V);
    finalize_kernel<<<B, 256, 0, stream>>>(
        partM, partS, partI, emb, out, embA0, embA1, s, Tp1, V, E);
  }
}

// Round 6
// 4826.978 us; speedup vs baseline: 2.6119x; 1.0067x over previous
//
#include <hip/hip_runtime.h>
#include <math.h>

// ---------------------------------------------------------------------------
// Sender: LSTM + Gumbel straight-through decode, 32 steps.
// Round 6: round-5 structure + fix finalize one-hot write race (the zero
// float4 covering tok and the sc write came from different threads with no
// ordering). Now each thread builds its float4 in-register and stores once.
//   GEMMs: 128 thr / 2 waves, tile 128(M)x64(N), wave tile 64x64, BK=32,
//   24KB LDS, 512 blocks = 2 blocks/CU. f16 2-way split (3 MFMA/product).
//   Fused epilogues: gates->LSTM cell; logits->sampling partials.
// ---------------------------------------------------------------------------

typedef _Float16 f16;
typedef f16 f16x8 __attribute__((ext_vector_type(8)));
typedef float f32x4 __attribute__((ext_vector_type(4)));

#define F16_MIN_NORM 6.104e-5f

__device__ __forceinline__ void split_f16(float v, f16& h, f16& l) {
  f16 h0 = (fabsf(v) < F16_MIN_NORM) ? (f16)0.0f : (f16)v;
  float r = (v - (float)h0) * 4096.0f;
  h = h0; l = (f16)r;
}

__device__ __forceinline__ float sigm(float x) { return 1.0f / (1.0f + expf(-x)); }

#define GLOAD_LDS16(gsrc, ldst)                                               \
  __builtin_amdgcn_global_load_lds(                                           \
      (const __attribute__((address_space(1))) unsigned int*)(const void*)(gsrc), \
      (__attribute__((address_space(3))) unsigned int*)(void*)(ldst), 16, 0, 0)

// --------------------------- threefry / gumbel -----------------------------

__device__ __forceinline__ unsigned tf_rotl(unsigned x, int r) {
  return (x << r) | (x >> (32 - r));
}

// JAX threefry2x32-20, key (0,42), partitionable: draw = x0_out ^ x1_out.
__device__ inline float gumbel_at(unsigned idx) {
  const unsigned ks0 = 0u;
  const unsigned ks1 = 42u;
  const unsigned ks2 = 0x1BD11BDAu ^ ks0 ^ ks1;
  unsigned x0 = 0u + ks0;
  unsigned x1 = idx + ks1;
#define TFR(rot) { x0 += x1; x1 = tf_rotl(x1, rot); x1 ^= x0; }
  TFR(13) TFR(15) TFR(26) TFR(6)
  x0 += ks1; x1 += ks2 + 1u;
  TFR(17) TFR(29) TFR(16) TFR(24)
  x0 += ks2; x1 += ks0 + 2u;
  TFR(13) TFR(15) TFR(26) TFR(6)
  x0 += ks0; x1 += ks1 + 3u;
  TFR(17) TFR(29) TFR(16) TFR(24)
  x0 += ks1; x1 += ks2 + 4u;
  TFR(13) TFR(15) TFR(26) TFR(6)
  x0 += ks2; x1 += ks0 + 5u;
#undef TFR
  const unsigned bits = x0 ^ x1;
  const float f = __uint_as_float((bits >> 9) | 0x3F800000u) - 1.0f;
  const float tiny = 1.17549435082228751e-38f;
  const float u = fmaxf(tiny, f * (1.0f - tiny) + tiny);
  return -logf(-logf(u));
}

// ------------------------- setup / pack kernels ----------------------------

__global__ void init_kernel(float* __restrict__ out, const float* __restrict__ emb,
                            f16* __restrict__ e0, f16* __restrict__ e1,
                            const int* __restrict__ startp, int Tp1, int V, int E) {
  const int b = blockIdx.x;
  const int start = *startp;
  float* orow = out + (size_t)b * Tp1 * V;
  const int tq = start >> 2;
  for (int v4 = threadIdx.x; v4 < V / 4; v4 += blockDim.x) {
    float4 v = make_float4(0.f, 0.f, 0.f, 0.f);
    if (v4 == tq) ((float*)&v)[start & 3] = 1.0f;
    ((float4*)orow)[v4] = v;
  }
  if (threadIdx.x < E) {
    const float v = emb[(size_t)start * E + threadIdx.x];
    f16 h, l; split_f16(v, h, l);
    e0[(size_t)b * E + threadIdx.x] = h;
    e1[(size_t)b * E + threadIdx.x] = l;
  }
}

// packed gate col p: gate q=(p>>4)&3, unit u=((p>>6)<<4)+(p&15); orig row
// n' = q*H + u. wpk[p][k] = k<E ? wih[n'][k] : whh[n'][k-E], split.
__global__ void pack_gates_kernel(const float* __restrict__ wih,
                                  const float* __restrict__ whh,
                                  f16* __restrict__ w0, f16* __restrict__ w1,
                                  int E, int H, int K) {
  const int k = blockIdx.x * blockDim.x + threadIdx.x;
  const int p = blockIdx.y;
  if (k >= K) return;
  const int n = ((p >> 4) & 3) * H + ((p >> 6) << 4) + (p & 15);
  const float v = (k < E) ? wih[(size_t)n * E + k] : whh[(size_t)n * H + (k - E)];
  f16 h, l; split_f16(v, h, l);
  w0[(size_t)p * K + k] = h;
  w1[(size_t)p * K + k] = l;
}

__global__ void pack_bias_kernel(const float* __restrict__ bih,
                                 const float* __restrict__ bhh,
                                 float* __restrict__ bi, float* __restrict__ bh, int H) {
  const int p = blockIdx.x * blockDim.x + threadIdx.x;
  const int n = ((p >> 4) & 3) * H + ((p >> 6) << 4) + (p & 15);
  bi[p] = bih[n];
  bh[p] = bhh[n];
}

__global__ void split_kernel(const float* __restrict__ in,
                             f16* __restrict__ o0, f16* __restrict__ o1, int n) {
  const int i = blockIdx.x * blockDim.x + threadIdx.x;
  if (i < n) { f16 h, l; split_f16(in[i], h, l); o0[i] = h; o1[i] = l; }
}

// ----------------------- shared K-loop building block ----------------------
// block 128 thr / 2 waves, tile 128x64, BK=32. wave0 stages hi planes,
// wave1 stages lo planes. lane->LDS: row lane>>2, col (lane&3)*8 (16B/lane).

#define MFMA_DECLS                                                            \
  const int tid  = threadIdx.x;                                               \
  const int lane = tid & 63;                                                  \
  const int wid  = tid >> 6;                                                  \
  const int bm   = blockIdx.y * 128;                                          \
  const int bn   = blockIdx.x * 64;                                           \
  const int wm   = wid * 64;                                                  \
  const int fr   = lane & 15;                                                 \
  const int fk   = (lane >> 4) * 8;                                           \
  const int srow = lane >> 2;                                                 \
  const int scol = (lane & 3) * 8;                                            \
  f32x4 acc0[4][4], acc1[4][4];                                               \
  _Pragma("unroll") for (int i = 0; i < 4; ++i)                               \
  _Pragma("unroll") for (int j = 0; j < 4; ++j) {                             \
    acc0[i][j] = (f32x4)0.0f; acc1[i][j] = (f32x4)0.0f; }

#define MFMA_STAGE(a0s, a1s, lda, ka, b0s, b1s, ldb, kb)                      \
  __syncthreads();                                                            \
  if (wid == 0) {                                                             \
    _Pragma("unroll") for (int s = 0; s < 8; ++s)                             \
      GLOAD_LDS16((a0s) + (size_t)(bm + s * 16 + srow) * (lda) + (ka) + scol, \
                  &ldsA0[s * 16][0]);                                         \
    _Pragma("unroll") for (int s = 0; s < 4; ++s)                             \
      GLOAD_LDS16((b0s) + (size_t)(bn + s * 16 + srow) * (ldb) + (kb) + scol, \
                  &ldsB0[s * 16][0]);                                         \
  } else {                                                                    \
    _Pragma("unroll") for (int s = 0; s < 8; ++s)                             \
      GLOAD_LDS16((a1s) + (size_t)(bm + s * 16 + srow) * (lda) + (ka) + scol, \
                  &ldsA1[s * 16][0]);                                         \
    _Pragma("unroll") for (int s = 0; s < 4; ++s)                             \
      GLOAD_LDS16((b1s) + (size_t)(bn + s * 16 + srow) * (ldb) + (kb) + scol, \
                  &ldsB1[s * 16][0]);                                         \
  }                                                                           \
  __syncthreads();

#define MFMA_COMPUTE                                                          \
  {                                                                           \
    f16x8 a0[4], a1[4], b0[4], b1[4];                                         \
    _Pragma("unroll") for (int i = 0; i < 4; ++i) {                           \
      a0[i] = *(const f16x8*)&ldsA0[wm + i * 16 + fr][fk];                    \
      a1[i] = *(const f16x8*)&ldsA1[wm + i * 16 + fr][fk];                    \
      b0[i] = *(const f16x8*)&ldsB0[i * 16 + fr][fk];                         \
      b1[i] = *(const f16x8*)&ldsB1[i * 16 + fr][fk];                         \
    }                                                                         \
    _Pragma("unroll") for (int i = 0; i < 4; ++i)                             \
    _Pragma("unroll") for (int j = 0; j < 4; ++j) {                           \
      acc0[i][j] = __builtin_amdgcn_mfma_f32_16x16x32_f16(a0[i], b0[j], acc0[i][j], 0, 0, 0); \
      acc1[i][j] = __builtin_amdgcn_mfma_f32_16x16x32_f16(a0[i], b1[j], acc1[i][j], 0, 0, 0); \
      acc1[i][j] = __builtin_amdgcn_mfma_f32_16x16x32_f16(a1[i], b0[j], acc1[i][j], 0, 0, 0); \
    }                                                                         \
  }

// ------------------- h0 GEMM: h0 = t @ aff_w^T + aff_b ---------------------
__global__ __launch_bounds__(128, 1) void h0_kernel(
    const f16* __restrict__ t0, const f16* __restrict__ t1, int F,
    const f16* __restrict__ aw0, const f16* __restrict__ aw1,
    const float* __restrict__ affb,
    f16* __restrict__ h0p, f16* __restrict__ h1p, int H,
    float* __restrict__ czero)
{
  __shared__ f16 ldsA0[128][32], ldsA1[128][32], ldsB0[64][32], ldsB1[64][32];
  MFMA_DECLS
  for (int kk = 0; kk < F; kk += 32) {
    MFMA_STAGE(t0, t1, F, kk, aw0, aw1, F, kk)
    MFMA_COMPUTE
  }
  const int q4 = (lane >> 4) * 4;
  const float s12 = 1.0f / 4096.0f;
#pragma unroll
  for (int j = 0; j < 4; ++j) {
    const int col = bn + j * 16 + fr;
    const float bb = affb[col];
#pragma unroll
    for (int i = 0; i < 4; ++i) {
#pragma unroll
      for (int r = 0; r < 4; ++r) {
        const int row = bm + wm + i * 16 + q4 + r;
        const float v = (acc0[i][j][r] + acc1[i][j][r] * s12) + bb;
        f16 hh, hl; split_f16(v, hh, hl);
        const size_t off = (size_t)row * H + col;
        h0p[off] = hh; h1p[off] = hl;
        czero[off] = 0.0f;
      }
    }
  }
}

// ---------------- gates GEMM + fused LSTM cell epilogue --------------------
__global__ __launch_bounds__(128, 1) void gates_kernel(
    const f16* __restrict__ e0, const f16* __restrict__ e1, int E,
    const f16* __restrict__ hin0, const f16* __restrict__ hin1, int H,
    const f16* __restrict__ w0, const f16* __restrict__ w1, int K,
    const float* __restrict__ bi, const float* __restrict__ bh,
    float* __restrict__ cbuf,
    f16* __restrict__ hout0, f16* __restrict__ hout1)
{
  __shared__ f16 ldsA0[128][32], ldsA1[128][32], ldsB0[64][32], ldsB1[64][32];
  MFMA_DECLS
  for (int kk = 0; kk < K; kk += 32) {
    const f16* a0s; const f16* a1s; int lda, ka;
    if (kk < E) { a0s = e0;   a1s = e1;   lda = E; ka = kk; }
    else        { a0s = hin0; a1s = hin1; lda = H; ka = kk - E; }
    MFMA_STAGE(a0s, a1s, lda, ka, w0, w1, K, kk)
    MFMA_COMPUTE
  }
  // epilogue: packed cols -> unit u = (bn>>2)+fr, gate q = j.
  const int q4 = (lane >> 4) * 4;
  const float s12 = 1.0f / 4096.0f;
  float biv[4], bhv[4];
#pragma unroll
  for (int j = 0; j < 4; ++j) {
    const int col = bn + j * 16 + fr;
    biv[j] = bi[col]; bhv[j] = bh[col];
  }
  const int nunit = (bn >> 2) + fr;
#pragma unroll
  for (int i = 0; i < 4; ++i) {
#pragma unroll
    for (int r = 0; r < 4; ++r) {
      const int row = bm + wm + i * 16 + q4 + r;
      float gv[4];
#pragma unroll
      for (int j = 0; j < 4; ++j)
        gv[j] = ((acc0[i][j][r] + acc1[i][j][r] * s12) + biv[j]) + bhv[j];
      const size_t off = (size_t)row * H + nunit;
      const float c = cbuf[off];
      const float cn = __fadd_rn(__fmul_rn(sigm(gv[1]), c),
                                 __fmul_rn(sigm(gv[0]), tanhf(gv[2])));
      const float hn = __fmul_rn(sigm(gv[3]), tanhf(cn));
      cbuf[off] = cn;
      f16 hh, hl; split_f16(hn, hh, hl);
      hout0[off] = hh; hout1[off] = hl;
    }
  }
}

// ------------- logits GEMM + fused sampling partials epilogue --------------
__global__ __launch_bounds__(128, 1) void logits_kernel(
    const f16* __restrict__ h0p, const f16* __restrict__ h1p, int H,
    const f16* __restrict__ w0, const f16* __restrict__ w1,
    const float* __restrict__ lpb,
    float* __restrict__ partM, float* __restrict__ partS, int* __restrict__ partI,
    int step, int B, int V)
{
  __shared__ f16 ldsA0[128][32], ldsA1[128][32], ldsB0[64][32], ldsB1[64][32];
  MFMA_DECLS
  for (int kk = 0; kk < H; kk += 32) {
    MFMA_STAGE(h0p, h1p, H, kk, w0, w1, H, kk)
    MFMA_COMPUTE
  }
  const int q4 = (lane >> 4) * 4;
  const float s12 = 1.0f / 4096.0f;
  float bv[4];
#pragma unroll
  for (int j = 0; j < 4; ++j) bv[j] = lpb[bn + j * 16 + fr];
  // w = logit + gumbel, overwrite acc0
#pragma unroll
  for (int i = 0; i < 4; ++i)
#pragma unroll
    for (int j = 0; j < 4; ++j) {
      const int col = bn + j * 16 + fr;
#pragma unroll
      for (int r = 0; r < 4; ++r) {
        const int row = bm + wm + i * 16 + q4 + r;
        const float logit = (acc0[i][j][r] + acc1[i][j][r] * s12) + bv[j];
        const unsigned gidx = ((unsigned)(step * B + row)) * (unsigned)V + (unsigned)col;
        acc0[i][j][r] = logit + gumbel_at(gidx);
      }
    }
  // per-row reduce over this block's 64 cols (within each 16-lane group)
  const int grp = bn >> 6;   // == blockIdx.x
#pragma unroll
  for (int i = 0; i < 4; ++i) {
#pragma unroll
    for (int r = 0; r < 4; ++r) {
      float mx = -INFINITY; int ix = 0;
#pragma unroll
      for (int j = 0; j < 4; ++j) {
        const float w = acc0[i][j][r];
        const int col = bn + j * 16 + fr;
        if (w > mx) { mx = w; ix = col; }
      }
#pragma unroll
      for (int m = 1; m < 16; m <<= 1) {
        const float om = __shfl_xor(mx, m, 64);
        const int oi = __shfl_xor(ix, m, 64);
        if (om > mx || (om == mx && oi < ix)) { mx = om; ix = oi; }
      }
      float s = 0.0f;
#pragma unroll
      for (int j = 0; j < 4; ++j) s += expf((acc0[i][j][r] - mx) / 1.2f);
#pragma unroll
      for (int m = 1; m < 16; m <<= 1) s += __shfl_xor(s, m, 64);
      if (fr == 0) {
        const int row = bm + wm + i * 16 + q4 + r;
        partM[(size_t)row * 64 + grp] = mx;
        partS[(size_t)row * 64 + grp] = s;
        partI[(size_t)row * 64 + grp] = ix;
      }
    }
  }
}

// ---------------- finalize: reduce partials, write, next emb ---------------
__global__ __launch_bounds__(256) void finalize_kernel(
    const float* __restrict__ partM, const float* __restrict__ partS,
    const int* __restrict__ partI,
    const float* __restrict__ emb,
    float* __restrict__ out,
    f16* __restrict__ e0, f16* __restrict__ e1,
    int step, int Tp1, int V, int E)
{
  const int b = blockIdx.x;
  const int tid = threadIdx.x;
  __shared__ float s_sc;
  __shared__ int s_tok;

  if (tid < 64) {
    const float m0 = partM[(size_t)b * 64 + tid];
    const float s0 = partS[(size_t)b * 64 + tid];
    const int i0 = partI[(size_t)b * 64 + tid];
    float mx = m0; int ix = i0;
#pragma unroll
    for (int m = 1; m < 64; m <<= 1) {
      const float om = __shfl_xor(mx, m, 64);
      const int oi = __shfl_xor(ix, m, 64);
      if (om > mx || (om == mx && oi < ix)) { mx = om; ix = oi; }
    }
    float c = s0 * expf((m0 - mx) / 1.2f);
#pragma unroll
    for (int m = 1; m < 64; m <<= 1) c += __shfl_xor(c, m, 64);
    if (tid == 0) {
      const float y = 1.0f / c;
      s_sc = (1.0f - y) + y;
      s_tok = ix;
    }
  }
  __syncthreads();
  const float sc = s_sc;
  const int tok = s_tok;

  // one-hot write: each thread builds its float4 in-register (no race)
  float* orow = out + ((size_t)b * Tp1 + step + 1) * V;
  const int tq = tok >> 2;
#pragma unroll
  for (int j = 0; j < 4; ++j) {
    const int idx = tid + 256 * j;
    float4 v = make_float4(0.f, 0.f, 0.f, 0.f);
    if (idx == tq) ((float*)&v)[tok & 3] = sc;
    ((float4*)orow)[idx] = v;
  }

  if (tid < E) {
    const float ev = sc * emb[(size_t)tok * E + tid];
    f16 h, l; split_f16(ev, h, l);
    e0[(size_t)b * E + tid] = h;
    e1[(size_t)b * E + tid] = l;
  }
}

// ------------------------------- host side ---------------------------------

extern "C" void kernel_launch(void* const* d_in, const int* in_sizes, int n_in,
                              void* d_out, int out_size, void* d_ws, size_t ws_size,
                              hipStream_t stream) {
  const float* t     = (const float*)d_in[0];
  const float* emb   = (const float*)d_in[1];
  const float* affw  = (const float*)d_in[2];
  const float* affb  = (const float*)d_in[3];
  const float* wih   = (const float*)d_in[4];
  const float* whh   = (const float*)d_in[5];
  const float* bih   = (const float*)d_in[6];
  const float* bhh   = (const float*)d_in[7];
  const float* lpw   = (const float*)d_in[8];
  const float* lpb   = (const float*)d_in[9];
  const int*   start = (const int*)d_in[10];
  float* out = (float*)d_out;

  const int H = in_sizes[3];             // 1024
  const int V = in_sizes[9];             // 4096
  const int E = in_sizes[1] / V;         // 256
  const int F = in_sizes[2] / H;         // 2048
  const int B = in_sizes[0] / F;         // 1024
  const int Tp1 = out_size / (B * V);    // 33
  const int T = Tp1 - 1;                 // 32
  const int KG = E + H;                  // 1280

  // ---- workspace layout (~65 MB) ----
  char* p = (char*)d_ws;
  float* cbuf  = (float*)p; p += (size_t)B * H * 4;           // 4 MB
  f16* hA0[2]; f16* hA1[2];
  hA0[0] = (f16*)p; p += (size_t)B * H * 2;
  hA1[0] = (f16*)p; p += (size_t)B * H * 2;
  hA0[1] = (f16*)p; p += (size_t)B * H * 2;
  hA1[1] = (f16*)p; p += (size_t)B * H * 2;                   // 8 MB
  f16* embA0 = (f16*)p; p += (size_t)B * E * 2;
  f16* embA1 = (f16*)p; p += (size_t)B * E * 2;               // 1 MB
  f16* wg0 = (f16*)p; p += (size_t)V * KG * 2;                // 20 MB packed gates
  f16* wg1 = (f16*)p; p += (size_t)V * KG * 2;
  f16* wl0 = (f16*)p; p += (size_t)V * H * 2;                 // 16 MB lp_w
  f16* wl1 = (f16*)p; p += (size_t)V * H * 2;
  f16* t0  = (f16*)p; p += (size_t)B * F * 2;                 // 8 MB t planes
  f16* t1  = (f16*)p; p += (size_t)B * F * 2;
  f16* aw0 = (f16*)p; p += (size_t)H * F * 2;                 // 8 MB aff_w planes
  f16* aw1 = (f16*)p; p += (size_t)H * F * 2;
  float* bgi = (float*)p; p += (size_t)V * 4;
  float* bgh = (float*)p; p += (size_t)V * 4;
  float* partM = (float*)p; p += (size_t)B * 64 * 4;
  float* partS = (float*)p; p += (size_t)B * 64 * 4;
  int*   partI = (int*)p;   p += (size_t)B * 64 * 4;
  (void)ws_size; (void)n_in;

  // ---- setup ----
  init_kernel<<<B, 256, 0, stream>>>(out, emb, embA0, embA1, start, Tp1, V, E);
  pack_gates_kernel<<<dim3((KG + 255) / 256, V), 256, 0, stream>>>(
      wih, whh, wg0, wg1, E, H, KG);
  pack_bias_kernel<<<V / 256, 256, 0, stream>>>(bih, bhh, bgi, bgh, H);
  split_kernel<<<(V * H + 255) / 256, 256, 0, stream>>>(lpw, wl0, wl1, V * H);
  split_kernel<<<(B * F + 255) / 256, 256, 0, stream>>>(t, t0, t1, B * F);
  split_kernel<<<(H * F + 255) / 256, 256, 0, stream>>>(affw, aw0, aw1, H * F);
  // h0 = t @ aff_w^T + aff_b -> split into hA[0]; zero cbuf
  h0_kernel<<<dim3(H / 64, B / 128), 128, 0, stream>>>(
      t0, t1, F, aw0, aw1, affb, hA0[0], hA1[0], H, cbuf);

  for (int s = 0; s < T; ++s) {
    const int cur = s & 1, nxt = (s + 1) & 1;
    gates_kernel<<<dim3(V / 64, B / 128), 128, 0, stream>>>(
        embA0, embA1, E, hA0[cur], hA1[cur], H,
        wg0, wg1, KG, bgi, bgh, cbuf, hA0[nxt], hA1[nxt]);
    logits_kernel<<<dim3(V / 64, B / 128), 128, 0, stream>>>(
        hA0[nxt], hA1[nxt], H, wl0, wl1, lpb,
        partM, partS, partI, s, B, V);
    finalize_kernel<<<B, 256, 0, stream>>>(
        partM, partS, partI, emb, out, embA0, embA1, s, Tp1, V, E);
  }
}